// Round 2
// baseline (72.401 us; speedup 1.0000x reference)
//
#include <hip/hip_runtime.h>
#include <hip/hip_bf16.h>
#include <math.h>

// KAN layer, fully fused.  Problem: batch=512, N_IN=128, N_OUT=256, K=3, G=3.
// Math restructured as out = (1/128) * F(512x896) * W^T(256x896):
//   k = i*7 + t ; F[b][k] = B_t(x[b,i]) for t<6, swish(x[b,i]) for t=6
//   W[o][k] = c_spl[j]*c_basis[j][t] for t<6, c_res[j] for t=6   (j = o*128+i)
// Single kernel: each block builds its F-tile (16 batch rows) and W-tile
// (32 out rows) in LDS, then two waves MFMA the 16x32 output tile.
// Grid rows are identical by construction -> knots read from grid[0..9].

typedef short short8 __attribute__((ext_vector_type(8)));
typedef float f32x4 __attribute__((ext_vector_type(4)));

#define KDIM 896
#define KPAD 904   // +8 shorts: row stride = 452 dwords == 4 (mod 32) -> only
                   // 2-way LDS bank aliasing on fragment reads (free, m136)

static __device__ inline unsigned short bf16_bits(float f) {
    union { __hip_bfloat16 h; unsigned short u; } cvt;
    cvt.h = __float2bfloat16(f);
    return cvt.u;
}

__global__ __launch_bounds__(128) void kan_fused(
    const float* __restrict__ x,        // (512,128)
    const float* __restrict__ grid,     // (32768,10) -- rows identical
    const float* __restrict__ c_basis,  // (32768,6)
    const float* __restrict__ c_spl,    // (32768,)
    const float* __restrict__ c_res,    // (32768,)
    float* __restrict__ out)            // (512,256) f32
{
    extern __shared__ __align__(16) unsigned short smem[];
    unsigned short* Fs = smem;              // 16 x KPAD
    unsigned short* Ws = smem + 16 * KPAD;  // 32 x KPAD

    const int bt  = blockIdx.x >> 3;   // 0..31 : batch tile (16 rows)
    const int ot  = blockIdx.x & 7;    // 0..7  : out tile   (32 rows)
    const int tid = threadIdx.x;       // 0..127

    // knot vector (uniform); hoist reciprocals of the 3 denominator spacings
    float t[10];
#pragma unroll
    for (int m = 0; m < 10; ++m) t[m] = grid[m];
    const float ih1 = 1.0f / (t[1] - t[0]);
    const float ih2 = 1.0f / (t[2] - t[0]);
    const float ih3 = 1.0f / (t[3] - t[0]);

    // ---- Phase A1: spline features, 16 rows x 128 i (thread = column i) ----
#pragma unroll 4
    for (int p = 0; p < 16; ++p) {
        const float xv = x[(bt * 16 + p) * 128 + tid];

        float b0[9];
#pragma unroll
        for (int s = 0; s < 9; ++s)
            b0[s] = (xv >= t[s] && xv < t[s + 1]) ? 1.0f : 0.0f;
        float b1[8];
#pragma unroll
        for (int s = 0; s < 8; ++s)
            b1[s] = (xv - t[s]) * ih1 * b0[s] + (t[s + 2] - xv) * ih1 * b0[s + 1];
        float b2[7];
#pragma unroll
        for (int s = 0; s < 7; ++s)
            b2[s] = (xv - t[s]) * ih2 * b1[s] + (t[s + 3] - xv) * ih2 * b1[s + 1];
        float b3[6];
#pragma unroll
        for (int s = 0; s < 6; ++s)
            b3[s] = (xv - t[s]) * ih3 * b2[s] + (t[s + 4] - xv) * ih3 * b2[s + 1];

        const float sw = xv / (1.0f + expf(-xv));

        unsigned short* dst = Fs + p * KPAD + tid * 7;
#pragma unroll
        for (int s = 0; s < 6; ++s) dst[s] = bf16_bits(b3[s]);
        dst[6] = bf16_bits(sw);
    }

    // ---- Phase A2: folded weights, 32 rows x 128 i (thread = column i) ----
#pragma unroll 4
    for (int p = 0; p < 32; ++p) {
        const int j = (ot * 32 + p) * 128 + tid;
        const float spl = c_spl[j];
        unsigned short* dst = Ws + p * KPAD + tid * 7;
#pragma unroll
        for (int s = 0; s < 6; ++s) dst[s] = bf16_bits(spl * c_basis[j * 6 + s]);
        dst[6] = bf16_bits(c_res[j]);
    }

    __syncthreads();

    // ---- Phase C: two waves, each one 16x16 MFMA quadrant, K = 896 ----
    const int lane = tid & 63;
    const int w    = tid >> 6;         // which 16-column half of the o-tile
    const int r    = lane & 15;
    const int q    = lane >> 4;

    const unsigned short* fa = Fs + r * KPAD + q * 8;
    const unsigned short* wb = Ws + (w * 16 + r) * KPAD + q * 8;

    f32x4 acc0 = {0.f, 0.f, 0.f, 0.f};
    f32x4 acc1 = {0.f, 0.f, 0.f, 0.f};   // two chains: break dependent-MFMA latency

#pragma unroll
    for (int k0 = 0; k0 < KDIM; k0 += 64) {
        short8 a0 = *(const short8*)(fa + k0);
        short8 a1 = *(const short8*)(fa + k0 + 32);
        short8 b0 = *(const short8*)(wb + k0);
        short8 b1 = *(const short8*)(wb + k0 + 32);
        acc0 = __builtin_amdgcn_mfma_f32_16x16x32_bf16(a0, b0, acc0, 0, 0, 0);
        acc1 = __builtin_amdgcn_mfma_f32_16x16x32_bf16(a1, b1, acc1, 0, 0, 0);
    }

    // C/D map (m89-verified): col = lane&15 (o), row = (lane>>4)*4+reg (b)
    const float scale = 1.0f / 128.0f;
    const int orow0 = bt * 16 + q * 4;
    const int ocol  = ot * 32 + w * 16 + r;
#pragma unroll
    for (int e = 0; e < 4; ++e)
        out[(orow0 + e) * 256 + ocol] = (acc0[e] + acc1[e]) * scale;
}

extern "C" void kernel_launch(void* const* d_in, const int* in_sizes, int n_in,
                              void* d_out, int out_size, void* d_ws, size_t ws_size,
                              hipStream_t stream) {
    const float* x       = (const float*)d_in[0];
    const float* grid    = (const float*)d_in[1];
    const float* c_basis = (const float*)d_in[2];
    const float* c_spl   = (const float*)d_in[3];
    const float* c_res   = (const float*)d_in[4];
    float* out = (float*)d_out;

    const size_t smem_bytes = (16 + 32) * KPAD * sizeof(unsigned short); // 86.8 KB
    // 32 batch-tiles x 8 out-tiles = 256 blocks (1 per CU), 128 threads each
    kan_fused<<<256, 128, smem_bytes, stream>>>(x, grid, c_basis, c_spl, c_res, out);
}

// Round 3
// 68.554 us; speedup vs baseline: 1.0561x; 1.0561x over previous
//
#include <hip/hip_runtime.h>
#include <hip/hip_bf16.h>
#include <math.h>

// KAN layer, fully fused, single launch.
// batch=512, N_IN=128, N_OUT=256, K=3, G=3; knots uniform t[m]=lo+(m-3)h, h=2/3.
// out = (1/128) * F(512x896) * W^T(256x896), k = i*7+t:
//   F[b][k] = B_t(x[b,i]) (t<6), swish(x[b,i]) (t=6)
//   W[o][k] = c_spl[j]*c_basis[j][t] (t<6), c_res[j] (t=6), j = o*128+i
// Uniform-knot closed form: with s = floor((x-t0)/h), u = frac, the only
// nonzero cubic basis values are pieces P0..P3 placed at slots t = s..s-3
// (slots outside [0,5] dropped) -- exactly the reference's truncated recursion.
//
// Block: 512 threads (8 waves), tile 16 batch x 32 out, grid 32x8=256 blocks.
// 8 waves = 2 o-halves x 4 K-quarters (224 each); LDS reduction for K-split.

typedef short short8 __attribute__((ext_vector_type(8)));
typedef float f32x4 __attribute__((ext_vector_type(4)));

#define KDIM 896
#define KPAD 904   // +8 shorts: stride 452 dwords == 4 (mod 32), low bank aliasing

static __device__ inline unsigned short bf16_bits(float f) {
    union { __hip_bfloat16 h; unsigned short u; } cvt;
    cvt.h = __float2bfloat16(f);
    return cvt.u;
}

__global__ __launch_bounds__(512) void kan_fused(
    const float* __restrict__ x,        // (512,128)
    const float* __restrict__ grid,     // (32768,10) -- rows identical
    const float* __restrict__ c_basis,  // (32768,6)
    const float* __restrict__ c_spl,    // (32768,)
    const float* __restrict__ c_res,    // (32768,)
    float* __restrict__ out)            // (512,256) f32
{
    extern __shared__ __align__(16) unsigned char smem[];
    unsigned short* Fs = (unsigned short*)smem;                    // 16 x KPAD
    unsigned short* Ws = Fs + 16 * KPAD;                           // 32 x KPAD
    float*          Red = (float*)(smem + 48 * KPAD * 2);          // 6 tiles x 256 f32

    const int bt  = blockIdx.x >> 3;   // 0..31 batch tile (16 rows)
    const int ot  = blockIdx.x & 7;    // 0..7  out tile   (32 rows)
    const int tid = threadIdx.x;       // 0..511
    const int col = tid & 127;         // i
    const int grp = tid >> 7;          // 0..3

    const float t0 = grid[0];
    const float ih = 1.0f / (grid[1] - grid[0]);

    // ---- build F: 16 rows, 4 per thread-group (closed-form basis + swish) ----
#pragma unroll
    for (int pp = 0; pp < 4; ++pp) {
        const int p  = grp * 4 + pp;
        const float xv = x[(bt * 16 + p) * 128 + col];

        const float xr = (xv - t0) * ih;
        const float sf = floorf(xr);
        const int   s  = (int)sf;
        const float u  = xr - sf;
        const float um = 1.0f - u;
        const float uu = u * u;
        const float p0 = (1.0f / 6.0f) * uu * u;
        const float p3 = (1.0f / 6.0f) * um * um * um;
        const float p1 = (1.0f / 6.0f) * (((-3.0f * u + 3.0f) * u + 3.0f) * u + 1.0f);
        const float p2 = (1.0f / 6.0f) * ((3.0f * u - 6.0f) * uu + 4.0f);

        unsigned short* dst = Fs + p * KPAD + col * 7;
#pragma unroll
        for (int t = 0; t < 6; ++t) {
            const int d = s - t;
            const float v = (d == 0) ? p0 : (d == 1) ? p1 : (d == 2) ? p2
                          : (d == 3) ? p3 : 0.0f;
            dst[t] = bf16_bits(v);
        }
        const float sw = xv / (1.0f + __expf(-xv));
        dst[6] = bf16_bits(sw);
    }

    // ---- build W: 32 rows, 8 per thread-group ----
#pragma unroll
    for (int pp = 0; pp < 8; ++pp) {
        const int p = grp * 8 + pp;
        const int j = (ot * 32 + p) * 128 + col;
        const float spl = c_spl[j];
        unsigned short* dst = Ws + p * KPAD + col * 7;
#pragma unroll
        for (int t = 0; t < 6; ++t) dst[t] = bf16_bits(spl * c_basis[j * 6 + t]);
        dst[6] = bf16_bits(c_res[j]);
    }

    __syncthreads();

    // ---- MFMA: 8 waves = 2 o-halves x 4 K-quarters (224 = 7 steps each) ----
    const int w    = tid >> 6;     // 0..7
    const int lane = tid & 63;
    const int r    = lane & 15;
    const int q    = lane >> 4;
    const int ho   = w & 1;        // o-half
    const int kq   = w >> 1;       // K-quarter

    const unsigned short* fa = Fs + r * KPAD + q * 8 + kq * 224;
    const unsigned short* wb = Ws + (ho * 16 + r) * KPAD + q * 8 + kq * 224;

    f32x4 acc0 = {0.f, 0.f, 0.f, 0.f};
    f32x4 acc1 = {0.f, 0.f, 0.f, 0.f};
#pragma unroll
    for (int k0 = 0; k0 < 192; k0 += 64) {
        short8 a0 = *(const short8*)(fa + k0);
        short8 b0 = *(const short8*)(wb + k0);
        short8 a1 = *(const short8*)(fa + k0 + 32);
        short8 b1 = *(const short8*)(wb + k0 + 32);
        acc0 = __builtin_amdgcn_mfma_f32_16x16x32_bf16(a0, b0, acc0, 0, 0, 0);
        acc1 = __builtin_amdgcn_mfma_f32_16x16x32_bf16(a1, b1, acc1, 0, 0, 0);
    }
    {
        short8 a0 = *(const short8*)(fa + 192);
        short8 b0 = *(const short8*)(wb + 192);
        acc0 = __builtin_amdgcn_mfma_f32_16x16x32_bf16(a0, b0, acc0, 0, 0, 0);
    }
    f32x4 acc;
#pragma unroll
    for (int e = 0; e < 4; ++e) acc[e] = acc0[e] + acc1[e];

    // ---- K-split reduction: kq>0 waves park partials in LDS ----
    if (kq > 0) {
        float* dst = Red + (((kq - 1) * 2 + ho) * 64 + lane) * 4;
        *(f32x4*)dst = acc;
    }
    __syncthreads();

    if (kq == 0) {
        const float* r0 = Red + ((0 * 2 + ho) * 64 + lane) * 4;
        const float* r1 = Red + ((1 * 2 + ho) * 64 + lane) * 4;
        const float* r2 = Red + ((2 * 2 + ho) * 64 + lane) * 4;
        const f32x4 v0 = *(const f32x4*)r0;
        const f32x4 v1 = *(const f32x4*)r1;
        const f32x4 v2 = *(const f32x4*)r2;

        // C/D map (m89-verified): col = lane&15 (o), row = (lane>>4)*4+e (b)
        const float scale = 1.0f / 128.0f;
        const int orow0 = bt * 16 + q * 4;
        const int ocol  = ot * 32 + ho * 16 + r;
#pragma unroll
        for (int e = 0; e < 4; ++e)
            out[(orow0 + e) * 256 + ocol] =
                (acc[e] + v0[e] + v1[e] + v2[e]) * scale;
    }
}

extern "C" void kernel_launch(void* const* d_in, const int* in_sizes, int n_in,
                              void* d_out, int out_size, void* d_ws, size_t ws_size,
                              hipStream_t stream) {
    const float* x       = (const float*)d_in[0];
    const float* grid    = (const float*)d_in[1];
    const float* c_basis = (const float*)d_in[2];
    const float* c_spl   = (const float*)d_in[3];
    const float* c_res   = (const float*)d_in[4];
    float* out = (float*)d_out;

    const size_t smem_bytes = 48 * KPAD * 2 + 6 * 256 * 4;  // 92928 B
    kan_fused<<<256, 512, smem_bytes, stream>>>(x, grid, c_basis, c_spl, c_res, out);
}